// Round 1
// baseline (92.846 us; speedup 1.0000x reference)
//
#include <hip/hip_runtime.h>

// Depthwise 4x4 blur ([1/8,3/8,3/8,1/8] separable), stride 2, reflect-pad 1.
// x: [8,128,256,256] f32  ->  y: [8,128,128,128] f32
//
// One thread = 4 consecutive output cols (one float4 store).
// Per input row: two aligned float4 loads + 2 edge scalars cover the 10
// needed columns; horizontal taps reuse registers, vertical reuse hits L2.

__global__ __launch_bounds__(256) void ds2d_kernel(const float* __restrict__ x,
                                                   float* __restrict__ y) {
    constexpr float k0 = 0.125f, k1 = 0.375f;
    constexpr int W = 256;      // input width == height
    constexpr int OW = 128;     // output width == height

    const int tid = blockIdx.x * 256 + threadIdx.x;
    const int t   = tid & 31;           // quad index within output row (128/4)
    const int oh  = (tid >> 5) & 127;   // output row
    const int nc  = tid >> 12;          // fused N*C plane index (8*128 = 1024)
    const int owb = t * 4;              // first output col of this thread
    const int cb  = owb * 2;            // leftmost aligned input col (=8t)

    const float* __restrict__ base = x + (size_t)nc * (W * W);

    // reflect-mapped scalar edge columns (only t==0 / t==31 actually reflect)
    int cl = cb - 1;  if (cl < 0) cl = 1;                 // -1 -> 1
    int cr = cb + 8;  if (cr > W - 1) cr = 2 * W - 2 - cr; // 256 -> 254

    float acc0 = 0.f, acc1 = 0.f, acc2 = 0.f, acc3 = 0.f;

    #pragma unroll
    for (int j = 0; j < 4; ++j) {
        int r = 2 * oh - 1 + j;
        if (r < 0) r = -r;
        else if (r > W - 1) r = 2 * W - 2 - r;
        const float* __restrict__ row = base + r * W;

        const float  a  = row[cl];
        const float4 f0 = *reinterpret_cast<const float4*>(row + cb);
        const float4 f1 = *reinterpret_cast<const float4*>(row + cb + 4);
        const float  d  = row[cr];

        // horizontal 4-tap at the 4 output positions
        const float h0 = k0 * (a    + f0.z) + k1 * (f0.x + f0.y);
        const float h1 = k0 * (f0.y + f1.x) + k1 * (f0.z + f0.w);
        const float h2 = k0 * (f0.w + f1.z) + k1 * (f1.x + f1.y);
        const float h3 = k0 * (f1.y + d   ) + k1 * (f1.z + f1.w);

        const float kv = (j == 0 || j == 3) ? k0 : k1;
        acc0 += kv * h0;
        acc1 += kv * h1;
        acc2 += kv * h2;
        acc3 += kv * h3;
    }

    float4 outv = make_float4(acc0, acc1, acc2, acc3);
    *reinterpret_cast<float4*>(y + ((size_t)nc * OW + oh) * OW + owb) = outv;
}

extern "C" void kernel_launch(void* const* d_in, const int* in_sizes, int n_in,
                              void* d_out, int out_size, void* d_ws, size_t ws_size,
                              hipStream_t stream) {
    const float* x = (const float*)d_in[0];
    float* y = (float*)d_out;

    // total outputs = 8*128*128*128 = 16,777,216 ; 4 per thread
    const int threads_total = 16777216 / 4;   // 4,194,304
    const int block = 256;
    const int grid = threads_total / block;   // 16384, exact

    ds2d_kernel<<<grid, block, 0, stream>>>(x, y);
}

// Round 2
// 71.525 us; speedup vs baseline: 1.2981x; 1.2981x over previous
//
#include <hip/hip_runtime.h>

// Depthwise 4x4 blur ([1/8,3/8,3/8,1/8] separable), stride 2, reflect-pad 1.
// x: [8,128,256,256] f32  ->  y: [8,128,128,128] f32
//
// One thread = 8 output rows x 4 output cols. Streams 18 input rows
// (2*8+2, vs 2 rows/output-row if uncached) computing the horizontal
// 4-tap ONCE per input row; vertical reuse lives in registers, not L2.
// Two rotating float4 accumulators (each input row feeds <=2 output rows);
// finished output rows are stored immediately.

__global__ __launch_bounds__(256) void ds2d_kernel(const float* __restrict__ x,
                                                   float* __restrict__ y) {
    constexpr float k0 = 0.125f, k1 = 0.375f;
    constexpr int W  = 256;     // input width == height
    constexpr int OW = 128;     // output width == height
    constexpr int HP = 8;       // output rows per thread

    const int tid = blockIdx.x * 256 + threadIdx.x;
    const int t   = tid & 31;           // col-quad within output row (128/4)
    const int s   = (tid >> 5) & 15;    // row strip (128/8)
    const int nc  = tid >> 9;           // fused N*C plane (8*128 = 1024)
    const int owb = t * 4;              // first output col
    const int cb  = owb * 2;            // leftmost aligned input col (=8t)
    const int oh0 = s * HP;             // first output row

    const float* __restrict__ base = x + (size_t)nc * (W * W);
    float* __restrict__ out = y + ((size_t)nc * OW + oh0) * OW + owb;

    // reflect-mapped scalar edge cols (only t==0 / t==31 actually reflect)
    int cl = cb - 1;  if (cl < 0) cl = 1;                  // -1  -> 1
    int cr = cb + 8;  if (cr > W - 1) cr = 2 * W - 2 - cr; // 256 -> 254

    const int row0 = oh0 * 2 - 1;       // first input row of this strip

    float acc[2][4];                    // rotating accumulators, parity = i&1
    #pragma unroll
    for (int p = 0; p < 2; ++p)
        #pragma unroll
        for (int c = 0; c < 4; ++c) acc[p][c] = 0.f;

    #pragma unroll
    for (int rl = 0; rl < 2 * HP + 2; ++rl) {      // 18 input rows
        int r = row0 + rl;
        r = (r < 0) ? -r : ((r > W - 1) ? 2 * W - 2 - r : r);
        const float* __restrict__ row = base + (r << 8);

        const float  a  = row[cl];
        const float4 f0 = *reinterpret_cast<const float4*>(row + cb);
        const float4 f1 = *reinterpret_cast<const float4*>(row + cb + 4);
        const float  d  = row[cr];

        // horizontal 4-tap at the 4 output positions (computed once per row)
        const float h0 = k0 * (a    + f0.z) + k1 * (f0.x + f0.y);
        const float h1 = k0 * (f0.y + f1.x) + k1 * (f0.z + f0.w);
        const float h2 = k0 * (f0.w + f1.z) + k1 * (f1.x + f1.y);
        const float h3 = k0 * (f1.y + d   ) + k1 * (f1.z + f1.w);

        // output row i uses input rows rl = 2i..2i+3 with weights [k0,k1,k1,k0]
        const int  m   = rl >> 1;
        const bool odd = (rl & 1) != 0;
        if (!odd) {
            if (m >= 1) {               // i = m-1, weight K[2] = k1
                float* A = acc[(m - 1) & 1];
                A[0] += k1 * h0; A[1] += k1 * h1; A[2] += k1 * h2; A[3] += k1 * h3;
            }
            if (m <= HP - 1) {          // i = m, weight K[0] = k0 (first touch)
                float* A = acc[m & 1];
                A[0] = k0 * h0; A[1] = k0 * h1; A[2] = k0 * h2; A[3] = k0 * h3;
            }
        } else {
            if (m >= 1) {               // i = m-1, weight K[3] = k0 -> row done
                float* A = acc[(m - 1) & 1];
                A[0] += k0 * h0; A[1] += k0 * h1; A[2] += k0 * h2; A[3] += k0 * h3;
                float4 o = make_float4(A[0], A[1], A[2], A[3]);
                *reinterpret_cast<float4*>(out + (size_t)(m - 1) * OW) = o;
            }
            if (m <= HP - 1) {          // i = m, weight K[1] = k1
                float* A = acc[m & 1];
                A[0] += k1 * h0; A[1] += k1 * h1; A[2] += k1 * h2; A[3] += k1 * h3;
            }
        }
    }
}

extern "C" void kernel_launch(void* const* d_in, const int* in_sizes, int n_in,
                              void* d_out, int out_size, void* d_ws, size_t ws_size,
                              hipStream_t stream) {
    const float* x = (const float*)d_in[0];
    float* y = (float*)d_out;

    // 1024 planes * 16 strips * 32 col-quads = 524,288 threads, exact
    const int block = 256;
    const int grid = (1024 * 16 * 32) / block;   // 2048
    ds2d_kernel<<<grid, block, 0, stream>>>(x, y);
}